// Round 6
// baseline (113.359 us; speedup 1.0000x reference)
//
#include <hip/hip_runtime.h>

#define NN 8192
#define BB 32
#define EMB 16
#define HID 64

typedef __attribute__((ext_vector_type(8))) short bf16x8;
typedef __attribute__((ext_vector_type(4))) float f32x4;

static __device__ inline unsigned short f2b(float f) {   // round-to-nearest-even
    union { float f; unsigned u; } v; v.f = f;
    return (unsigned short)((v.u + 0x7fffu + ((v.u >> 16) & 1u)) >> 16);
}

// pack two fp32 (truncate) into one dword of bf16: [hi16(odd) : hi16(even)]
static __device__ inline unsigned packbf(unsigned e_even, unsigned e_odd) {
#if __has_builtin(__builtin_amdgcn_perm)
    return __builtin_amdgcn_perm(e_odd, e_even, 0x07060302u);
#else
    return (e_odd & 0xFFFF0000u) | (e_even >> 16);
#endif
}

// ---------------------------------------------------------------------------
// K1: fragment prep (MFMA lane order).
//  bx [0,256):   VTf[c][u][lane]  : V fragments (PV A-operand)
//  bx [256,384): Afrag[c][h][lane]: adj m-rows (score A-operand, permuted)
//  bx [384,512): adjS[n][d] = bf16(adj*log2e)  (score B side, row-major)
// ---------------------------------------------------------------------------
__global__ void k_build(const float* __restrict__ x, const float* __restrict__ adj,
                        short* __restrict__ VTf, short* __restrict__ Afrag,
                        short* __restrict__ adjS) {
    const int t = threadIdx.x;
    const int bx = blockIdx.x;
    if (bx < 256) {
        const int c = bx;
        const int u = t >> 6, lane = t & 63, l = lane & 15, q = lane >> 4;
        const int j = 16 * u + l, b = j >> 1, ch = j & 1;
        const int m0 = 32 * c + 8 * q;
        const float* xp = x + (size_t)b * (NN * 2) + m0 * 2;
        uint4 d;
        unsigned dd[4];
#pragma unroll
        for (int i = 0; i < 4; ++i) {
            float4 xx = *(const float4*)(xp + 4 * i);
            float v0 = ch ? xx.y : xx.x;
            float v1 = ch ? xx.w : xx.z;
            dd[i] = (unsigned)f2b(v0) | ((unsigned)f2b(v1) << 16);
        }
        d.x = dd[0]; d.y = dd[1]; d.z = dd[2]; d.w = dd[3];
        *(uint4*)(VTf + ((size_t)(c * 4 + u) * 64 + lane) * 8) = d;
    } else if (bx < 384) {
        const int cc = t >> 7, tt = t & 127;
        const int c = (bx - 256) * 2 + cc;
        const int h = tt >> 6, lane = tt & 63, l = lane & 15, q = lane >> 4;
        const int row = 32 * c + 8 * (l >> 2) + (l & 3) + 4 * h;
        const float* ap = adj + (size_t)row * EMB + (q & 1) * 8;
        float4 a0 = *(const float4*)(ap);
        float4 a1 = *(const float4*)(ap + 4);
        uint4 d;
        d.x = (unsigned)f2b(a0.x) | ((unsigned)f2b(a0.y) << 16);
        d.y = (unsigned)f2b(a0.z) | ((unsigned)f2b(a0.w) << 16);
        d.z = (unsigned)f2b(a1.x) | ((unsigned)f2b(a1.y) << 16);
        d.w = (unsigned)f2b(a1.z) | ((unsigned)f2b(a1.w) << 16);
        *(uint4*)(Afrag + ((size_t)(c * 2 + h) * 64 + lane) * 8) = d;
    } else {
        const float L2E = 1.4426950408889634f;
        int idx = (bx - 384) * 256 + t;
        float4 aa = *(const float4*)(adj + (size_t)idx * 4);
        uint2 us;
        us.x = (unsigned)f2b(aa.x * L2E) | ((unsigned)f2b(aa.y * L2E) << 16);
        us.y = (unsigned)f2b(aa.z * L2E) | ((unsigned)f2b(aa.w * L2E) << 16);
        *(uint2*)(adjS + (size_t)idx * 4) = us;
    }
}

// ---------------------------------------------------------------------------
// K2a: flash propagation main loop. 256 blocks x 512 thr; block = (tile,mq)
// with tile = bx&63 (128 nodes), mq = bx>>6 (quarter m range). Per-block
// L2 fragment stream 0.375 MB (aggregate 192->96 MB vs R5). 8 waves split
// the 64-cg quarter-range, 8 cg each; wave covers all 128 n (8 B-frags).
// Denominator via fp32 VALU accumulation + shfl_xor reduce (saves the dacc
// MFMA and 24 VGPRs -> acc[4][8] fits under the 256-VGPR / 2-wave/SIMD cap).
// Wave partials meet in LDS; block fp32 partial + den written to global.
// ---------------------------------------------------------------------------
__launch_bounds__(512, 1)
__global__ void k_main(const short* __restrict__ Afrag, const short* __restrict__ adjS,
                       const short* __restrict__ VTf,
                       float* __restrict__ gnum, float* __restrict__ gden) {
    const int t = threadIdx.x;
    const int wv = t >> 6;
    const int lane = t & 63;
    const int l = lane & 15;
    const int q = lane >> 4;
    const int tile = blockIdx.x & 63;
    const int mq = blockIdx.x >> 6;
    const int n0 = tile * 128;
    const int cbeg = mq * 64 + wv * 8;
    const int cend = cbeg + 8;

    __shared__ __align__(16) unsigned short ysl[8][128][68];  // bf16 wave partials (139.3 KB)
    __shared__ float dsl[8][128];                             // 4 KB

    // loop-invariant score B-fragments (log2e-scaled), k>=16 zeroed; 8 x 16 n
    bf16x8 Bn[8];
    bf16x8 zv = {0, 0, 0, 0, 0, 0, 0, 0};
#pragma unroll
    for (int s = 0; s < 8; ++s) {
        const short* src = adjS + (size_t)(n0 + 16 * s + l) * EMB + (q & 1) * 8;
        bf16x8 v = *(const bf16x8*)src;
        Bn[s] = (q < 2) ? v : zv;
    }

    f32x4 acc[4][8];
    float pden[8];
#pragma unroll
    for (int u = 0; u < 4; ++u)
#pragma unroll
        for (int s = 0; s < 8; ++s) { acc[u][s][0] = acc[u][s][1] = acc[u][s][2] = acc[u][s][3] = 0.f; }
#pragma unroll
    for (int s = 0; s < 8; ++s) pden[s] = 0.f;

    const short* Ap = Afrag + (size_t)lane * 8;   // + cg*1024 + h*512
    const short* Vp = VTf + (size_t)lane * 8;     // + cg*2048 + u*512

    // prologue: A fragments for first subtile
    bf16x8 aCur0 = *(const bf16x8*)(Ap + (size_t)cbeg * 1024);
    bf16x8 aCur1 = *(const bf16x8*)(Ap + (size_t)cbeg * 1024 + 512);

    for (int cg = cbeg; cg < cend; ++cg) {
        bf16x8 v0 = *(const bf16x8*)(Vp + (size_t)cg * 2048);
        bf16x8 v1 = *(const bf16x8*)(Vp + (size_t)cg * 2048 + 512);
        bf16x8 v2 = *(const bf16x8*)(Vp + (size_t)cg * 2048 + 1024);
        bf16x8 v3 = *(const bf16x8*)(Vp + (size_t)cg * 2048 + 1536);
        const int cgn = (cg + 1 < cend) ? cg + 1 : cbeg;   // clamped redundant last
        bf16x8 aN0 = *(const bf16x8*)(Ap + (size_t)cgn * 1024);
        bf16x8 aN1 = *(const bf16x8*)(Ap + (size_t)cgn * 1024 + 512);

        const f32x4 z = {0.f, 0.f, 0.f, 0.f};
        // per-s fused score->exp->pack->PV keeps S transient (VGPR pressure)
#pragma unroll
        for (int s = 0; s < 8; ++s) {
            f32x4 S0 = __builtin_amdgcn_mfma_f32_16x16x32_bf16(aCur0, Bn[s], z, 0, 0, 0);
            f32x4 S1 = __builtin_amdgcn_mfma_f32_16x16x32_bf16(aCur1, Bn[s], z, 0, 0, 0);
            unsigned w0[4], w1[4];
            float psum = 0.f;
#pragma unroll
            for (int r = 0; r < 4; ++r) {
                union { float f; unsigned u; } p0, p1;
                p0.f = __builtin_amdgcn_exp2f(fmaxf(S0[r], 0.f));
                p1.f = __builtin_amdgcn_exp2f(fmaxf(S1[r], 0.f));
                psum += p0.f + p1.f;
                w0[r] = p0.u;      // j = r      (h=0)
                w1[r] = p1.u;      // j = 4 + r  (h=1)
            }
            pden[s] += psum;
            union { bf16x8 v; unsigned d[4]; } pf;
            pf.d[0] = packbf(w0[0], w0[1]);
            pf.d[1] = packbf(w0[2], w0[3]);
            pf.d[2] = packbf(w1[0], w1[1]);
            pf.d[3] = packbf(w1[2], w1[3]);
            acc[0][s] = __builtin_amdgcn_mfma_f32_16x16x32_bf16(v0, pf.v, acc[0][s], 0, 0, 0);
            acc[1][s] = __builtin_amdgcn_mfma_f32_16x16x32_bf16(v1, pf.v, acc[1][s], 0, 0, 0);
            acc[2][s] = __builtin_amdgcn_mfma_f32_16x16x32_bf16(v2, pf.v, acc[2][s], 0, 0, 0);
            acc[3][s] = __builtin_amdgcn_mfma_f32_16x16x32_bf16(v3, pf.v, acc[3][s], 0, 0, 0);
        }
        aCur0 = aN0;
        aCur1 = aN1;
    }

    // denominator: lanes {l, l+16, l+32, l+48} hold partials of n-col l
#pragma unroll
    for (int s = 0; s < 8; ++s) {
        float d = pden[s];
        d += __shfl_xor(d, 16, 64);
        d += __shfl_xor(d, 32, 64);
        pden[s] = d;
    }

    // dump this wave's partial (bf16 num, f32 den) into its LDS slot
#pragma unroll
    for (int s = 0; s < 8; ++s) {
        const int nl_w = 16 * s + l;
#pragma unroll
        for (int u = 0; u < 4; ++u) {
            union { float f; unsigned u; } a0, a1, a2, a3;
            a0.f = acc[u][s][0]; a1.f = acc[u][s][1]; a2.f = acc[u][s][2]; a3.f = acc[u][s][3];
            uint2 pk;
            pk.x = packbf(a0.u, a1.u);
            pk.y = packbf(a2.u, a3.u);
            *(uint2*)&ysl[wv][nl_w][16 * u + 4 * q] = pk;
        }
        if (q == 0) dsl[wv][nl_w] = pden[s];
    }
    __syncthreads();

    // block combine: fp32 partial [p=mq*64+tile][n(128)][64], den [p][128]
    float* gn = gnum + (size_t)(mq * 64 + tile) * 128 * 64;
    float* gd = gden + (size_t)(mq * 64 + tile) * 128;
    const int nl = t >> 4, og = t & 15;
#pragma unroll
    for (int h = 0; h < 4; ++h) {
        const int nr = nl + 32 * h;
        f32x4 ysum = {0.f, 0.f, 0.f, 0.f};
        float dsum = 0.f;
#pragma unroll
        for (int s = 0; s < 8; ++s) {
            ushort4 p = *(const ushort4*)&ysl[s][nr][og * 4];
            union { unsigned u; float f; } c0, c1, c2, c3;
            c0.u = (unsigned)p.x << 16; c1.u = (unsigned)p.y << 16;
            c2.u = (unsigned)p.z << 16; c3.u = (unsigned)p.w << 16;
            ysum[0] += c0.f; ysum[1] += c1.f; ysum[2] += c2.f; ysum[3] += c3.f;
            dsum += dsl[s][nr];
        }
        *(f32x4*)(gn + (size_t)nr * 64 + og * 4) = ysum;
        if (og == 0) gd[nr] = dsum;
    }
}

// ---------------------------------------------------------------------------
// K2b: epilogue. 256 blocks x 512 thr, 32 nodes each. Combines the four
// m-quarter fp32 partials (deterministic order), normalizes, computes
// node-adaptive W in fp32 from adj x wp/bp staged in LDS, writes out.
// ---------------------------------------------------------------------------
__global__ void k_epi3(const float* __restrict__ adj, const float* __restrict__ wp,
                       const float* __restrict__ bp, const float* __restrict__ x,
                       const float* __restrict__ gnum, const float* __restrict__ gden,
                       float* __restrict__ out) {
    const int t = threadIdx.x;
    const int nl = t >> 4, og = t & 15;           // nl in [0,32)
    const int tile = blockIdx.x >> 2;             // 128-node tile
    const int n0 = blockIdx.x * 32;               // global n base
    const int nloc = (blockIdx.x & 3) * 32 + nl;  // row within tile partial [0,128)
    const int n = n0 + nl;

    __shared__ float wpl[EMB][5][64];   // 20 KB: [d][c][j], c=4 is bias
    __shared__ float adjl[32][EMB];     // 2 KB
    __shared__ float xl[32][68];
    __shared__ float ylf[32][68];

    // stage wp/bp into LDS (fp32)
    for (int i = t; i < EMB * 5 * 64; i += 512) {
        const int d = i / 320, r = i % 320, c = r >> 6, j = r & 63;
        wpl[d][c][j] = (c < 4) ? wp[(size_t)(d * 4 + c) * 64 + j] : bp[(size_t)d * 64 + j];
    }
    // stage adj rows (one float per thread: 32 x 16 = 512)
    adjl[nl][og] = adj[(size_t)(n0 + nl) * EMB + og];

    // combine the four m-quarter partials (fixed order), normalize
    f32x4 ysum = {0.f, 0.f, 0.f, 0.f};
    float dsum = 0.f;
#pragma unroll
    for (int mqi = 0; mqi < 4; ++mqi) {
        const float* gn = gnum + (size_t)(mqi * 64 + tile) * 128 * 64;
        f32x4 y = *(const f32x4*)(gn + (size_t)nloc * 64 + og * 4);
        ysum[0] += y[0]; ysum[1] += y[1]; ysum[2] += y[2]; ysum[3] += y[3];
        dsum += gden[(size_t)(mqi * 64 + tile) * 128 + nloc];
    }
    float rden = 1.f / dsum;
    ylf[nl][og * 4 + 0] = ysum[0] * rden;
    ylf[nl][og * 4 + 1] = ysum[1] * rden;
    ylf[nl][og * 4 + 2] = ysum[2] * rden;
    ylf[nl][og * 4 + 3] = ysum[3] * rden;

    // stage x rows
    float2 x0 = *(const float2*)(x + ((size_t)(og * 2) * NN + n) * 2);
    float2 x1v = *(const float2*)(x + ((size_t)(og * 2 + 1) * NN + n) * 2);
    xl[nl][og * 4 + 0] = x0.x; xl[nl][og * 4 + 1] = x0.y;
    xl[nl][og * 4 + 2] = x1v.x; xl[nl][og * 4 + 3] = x1v.y;
    __syncthreads();

    // node-adaptive weights in fp32: W[c][j4] = sum_d adj[n][d] * wpl[d][c][j4]
    float4 W[5];
#pragma unroll
    for (int c = 0; c < 5; ++c) { W[c].x = W[c].y = W[c].z = W[c].w = 0.f; }
#pragma unroll
    for (int d = 0; d < EMB; ++d) {
        const float a = adjl[nl][d];
#pragma unroll
        for (int c = 0; c < 5; ++c) {
            const float4 p = *(const float4*)&wpl[d][c][og * 4];
            W[c].x += a * p.x; W[c].y += a * p.y; W[c].z += a * p.z; W[c].w += a * p.w;
        }
    }

#pragma unroll 4
    for (int b = 0; b < BB; ++b) {
        float xb0 = xl[nl][2 * b], xb1 = xl[nl][2 * b + 1];
        float yb0 = ylf[nl][2 * b], yb1 = ylf[nl][2 * b + 1];
        f32x4 o4;
        o4[0] = xb0 * W[0].x + xb1 * W[1].x + yb0 * W[2].x + yb1 * W[3].x + W[4].x;
        o4[1] = xb0 * W[0].y + xb1 * W[1].y + yb0 * W[2].y + yb1 * W[3].y + W[4].y;
        o4[2] = xb0 * W[0].z + xb1 * W[1].z + yb0 * W[2].z + yb1 * W[3].z + W[4].z;
        o4[3] = xb0 * W[0].w + xb1 * W[1].w + yb0 * W[2].w + yb1 * W[3].w + W[4].w;
        __builtin_nontemporal_store(o4, (f32x4*)(out + ((size_t)b * NN + n) * HID + og * 4));
    }
}

// ---------------------------------------------------------------------------
extern "C" void kernel_launch(void* const* d_in, const int* in_sizes, int n_in,
                              void* d_out, int out_size, void* d_ws, size_t ws_size,
                              hipStream_t stream) {
    const float* x   = (const float*)d_in[0];   // [32, 8192, 2]
    const float* adj = (const float*)d_in[1];   // [8192, 16]
    const float* wp  = (const float*)d_in[2];   // [16, 2, 2, 64]
    const float* bp  = (const float*)d_in[3];   // [16, 64]
    float* out = (float*)d_out;                 // [32, 8192, 64]

    char* w = (char*)d_ws;
    short* VTf   = (short*)w;                                   // 1 MB
    short* Afrag = VTf + (size_t)256 * 4 * 64 * 8;              // 512 KB
    short* adjS  = Afrag + (size_t)256 * 2 * 64 * 8;            // 256 KB
    float* gnum  = (float*)(adjS + (size_t)NN * EMB);           // 8.39 MB [256][128][64]
    float* gden  = gnum + (size_t)256 * 128 * 64;               // 128 KB  [256][128]

    k_build<<<512, 256, 0, stream>>>(x, adj, VTf, Afrag, adjS);
    k_main<<<256, 512, 0, stream>>>(Afrag, adjS, VTf, gnum, gden);
    k_epi3<<<256, 512, 0, stream>>>(adj, wp, bp, x, gnum, gden, out);
}

// Round 7
// 109.749 us; speedup vs baseline: 1.0329x; 1.0329x over previous
//
#include <hip/hip_runtime.h>

#define NN 8192
#define BB 32
#define EMB 16
#define HID 64

typedef __attribute__((ext_vector_type(8))) short bf16x8;
typedef __attribute__((ext_vector_type(4))) float f32x4;

static __device__ inline unsigned short f2b(float f) {   // round-to-nearest-even
    union { float f; unsigned u; } v; v.f = f;
    return (unsigned short)((v.u + 0x7fffu + ((v.u >> 16) & 1u)) >> 16);
}

// pack two fp32 (truncate) into one dword of bf16: [hi16(odd) : hi16(even)]
static __device__ inline unsigned packbf(unsigned e_even, unsigned e_odd) {
#if __has_builtin(__builtin_amdgcn_perm)
    return __builtin_amdgcn_perm(e_odd, e_even, 0x07060302u);
#else
    return (e_odd & 0xFFFF0000u) | (e_even >> 16);
#endif
}

// ---------------------------------------------------------------------------
// K1: fragment prep (MFMA lane order).
//  bx [0,256):   VTf[c][u][lane]  : V fragments (PV A-operand)
//  bx [256,384): Afrag[c][h][lane]: adj m-rows (score A-operand, permuted)
//  bx [384,512): adjS[n][d] = bf16(adj*log2e)  (score B side, row-major)
// ---------------------------------------------------------------------------
__global__ void k_build(const float* __restrict__ x, const float* __restrict__ adj,
                        short* __restrict__ VTf, short* __restrict__ Afrag,
                        short* __restrict__ adjS) {
    const int t = threadIdx.x;
    const int bx = blockIdx.x;
    if (bx < 256) {
        const int c = bx;
        const int u = t >> 6, lane = t & 63, l = lane & 15, q = lane >> 4;
        const int j = 16 * u + l, b = j >> 1, ch = j & 1;
        const int m0 = 32 * c + 8 * q;
        const float* xp = x + (size_t)b * (NN * 2) + m0 * 2;
        uint4 d;
        unsigned dd[4];
#pragma unroll
        for (int i = 0; i < 4; ++i) {
            float4 xx = *(const float4*)(xp + 4 * i);
            float v0 = ch ? xx.y : xx.x;
            float v1 = ch ? xx.w : xx.z;
            dd[i] = (unsigned)f2b(v0) | ((unsigned)f2b(v1) << 16);
        }
        d.x = dd[0]; d.y = dd[1]; d.z = dd[2]; d.w = dd[3];
        *(uint4*)(VTf + ((size_t)(c * 4 + u) * 64 + lane) * 8) = d;
    } else if (bx < 384) {
        const int cc = t >> 7, tt = t & 127;
        const int c = (bx - 256) * 2 + cc;
        const int h = tt >> 6, lane = tt & 63, l = lane & 15, q = lane >> 4;
        const int row = 32 * c + 8 * (l >> 2) + (l & 3) + 4 * h;
        const float* ap = adj + (size_t)row * EMB + (q & 1) * 8;
        float4 a0 = *(const float4*)(ap);
        float4 a1 = *(const float4*)(ap + 4);
        uint4 d;
        d.x = (unsigned)f2b(a0.x) | ((unsigned)f2b(a0.y) << 16);
        d.y = (unsigned)f2b(a0.z) | ((unsigned)f2b(a0.w) << 16);
        d.z = (unsigned)f2b(a1.x) | ((unsigned)f2b(a1.y) << 16);
        d.w = (unsigned)f2b(a1.z) | ((unsigned)f2b(a1.w) << 16);
        *(uint4*)(Afrag + ((size_t)(c * 2 + h) * 64 + lane) * 8) = d;
    } else {
        const float L2E = 1.4426950408889634f;
        int idx = (bx - 384) * 256 + t;
        float4 aa = *(const float4*)(adj + (size_t)idx * 4);
        uint2 us;
        us.x = (unsigned)f2b(aa.x * L2E) | ((unsigned)f2b(aa.y * L2E) << 16);
        us.y = (unsigned)f2b(aa.z * L2E) | ((unsigned)f2b(aa.w * L2E) << 16);
        *(uint2*)(adjS + (size_t)idx * 4) = us;
    }
}

// ---------------------------------------------------------------------------
// K2a: flash propagation main loop (R5 structure — verified best).
// 256 blocks x 512 thr; block = (tile,mhalf): tile = bx&127 (64 nodes),
// mhalf = bx>>7. 73 KB LDS -> 2 blocks/CU, 16 waves/CU (R6 showed 8 is a
// cliff). Wave partials (bf16) meet in LDS; block partial stored as BF16
// (RNE) -> gnum round trip 8 MB -> 4 MB vs R5. den stays fp32.
// ---------------------------------------------------------------------------
__launch_bounds__(512, 1)
__global__ void k_main(const short* __restrict__ Afrag, const short* __restrict__ adjS,
                       const short* __restrict__ VTf,
                       unsigned short* __restrict__ gnum, float* __restrict__ gden) {
    const int t = threadIdx.x;
    const int wv = t >> 6;
    const int lane = t & 63;
    const int l = lane & 15;
    const int q = lane >> 4;
    const int tile = blockIdx.x & 127;
    const int mh = blockIdx.x >> 7;
    const int n0 = tile * 64;
    const int cbeg = mh * 128 + wv * 16;
    const int cend = cbeg + 16;

    __shared__ __align__(16) unsigned short ysl[8][64][68];  // bf16 wave partials (69.6 KB)
    __shared__ float dsl[8][64];

    // loop-invariant score B-fragments (log2e-scaled), k>=16 zeroed; 4 x 16 n
    bf16x8 Bn[4];
    bf16x8 zv = {0, 0, 0, 0, 0, 0, 0, 0};
#pragma unroll
    for (int s = 0; s < 4; ++s) {
        const short* src = adjS + (size_t)(n0 + 16 * s + l) * EMB + (q & 1) * 8;
        bf16x8 v = *(const bf16x8*)src;
        Bn[s] = (q < 2) ? v : zv;
    }
    const short one = (short)0x3F80;
    bf16x8 ones = {one, one, one, one, one, one, one, one};

    f32x4 acc[4][4];
    f32x4 dacc[4];
#pragma unroll
    for (int u = 0; u < 4; ++u)
#pragma unroll
        for (int s = 0; s < 4; ++s) { acc[u][s][0] = acc[u][s][1] = acc[u][s][2] = acc[u][s][3] = 0.f; }
#pragma unroll
    for (int s = 0; s < 4; ++s) { dacc[s][0] = dacc[s][1] = dacc[s][2] = dacc[s][3] = 0.f; }

    const short* Ap = Afrag + (size_t)lane * 8;   // + cg*1024 + h*512
    const short* Vp = VTf + (size_t)lane * 8;     // + cg*2048 + u*512

    // prologue: A fragments for first subtile
    bf16x8 aCur0 = *(const bf16x8*)(Ap + (size_t)cbeg * 1024);
    bf16x8 aCur1 = *(const bf16x8*)(Ap + (size_t)cbeg * 1024 + 512);

    for (int cg = cbeg; cg < cend; ++cg) {
        bf16x8 v0 = *(const bf16x8*)(Vp + (size_t)cg * 2048);
        bf16x8 v1 = *(const bf16x8*)(Vp + (size_t)cg * 2048 + 512);
        bf16x8 v2 = *(const bf16x8*)(Vp + (size_t)cg * 2048 + 1024);
        bf16x8 v3 = *(const bf16x8*)(Vp + (size_t)cg * 2048 + 1536);
        const int cgn = (cg + 1 < cend) ? cg + 1 : cbeg;   // clamped redundant last
        bf16x8 aN0 = *(const bf16x8*)(Ap + (size_t)cgn * 1024);
        bf16x8 aN1 = *(const bf16x8*)(Ap + (size_t)cgn * 1024 + 512);

        f32x4 z = {0.f, 0.f, 0.f, 0.f};
        f32x4 S0[4], S1[4];
#pragma unroll
        for (int s = 0; s < 4; ++s) {
            S0[s] = __builtin_amdgcn_mfma_f32_16x16x32_bf16(aCur0, Bn[s], z, 0, 0, 0);
            S1[s] = __builtin_amdgcn_mfma_f32_16x16x32_bf16(aCur1, Bn[s], z, 0, 0, 0);
        }
#pragma unroll
        for (int s = 0; s < 4; ++s) {
            unsigned w0[4], w1[4];
#pragma unroll
            for (int r = 0; r < 4; ++r) {
                union { float f; unsigned u; } p0, p1;
                p0.f = __builtin_amdgcn_exp2f(fmaxf(S0[s][r], 0.f));
                p1.f = __builtin_amdgcn_exp2f(fmaxf(S1[s][r], 0.f));
                w0[r] = p0.u;      // j = r      (h=0)
                w1[r] = p1.u;      // j = 4 + r  (h=1)
            }
            union { bf16x8 v; unsigned d[4]; } pf;
            pf.d[0] = packbf(w0[0], w0[1]);
            pf.d[1] = packbf(w0[2], w0[3]);
            pf.d[2] = packbf(w1[0], w1[1]);
            pf.d[3] = packbf(w1[2], w1[3]);
            acc[0][s] = __builtin_amdgcn_mfma_f32_16x16x32_bf16(v0, pf.v, acc[0][s], 0, 0, 0);
            acc[1][s] = __builtin_amdgcn_mfma_f32_16x16x32_bf16(v1, pf.v, acc[1][s], 0, 0, 0);
            acc[2][s] = __builtin_amdgcn_mfma_f32_16x16x32_bf16(v2, pf.v, acc[2][s], 0, 0, 0);
            acc[3][s] = __builtin_amdgcn_mfma_f32_16x16x32_bf16(v3, pf.v, acc[3][s], 0, 0, 0);
            dacc[s] = __builtin_amdgcn_mfma_f32_16x16x32_bf16(ones, pf.v, dacc[s], 0, 0, 0);
        }
        aCur0 = aN0;
        aCur1 = aN1;
    }

    // dump this wave's partial (bf16 num, f32 den) into its LDS slot
#pragma unroll
    for (int s = 0; s < 4; ++s) {
        const int nl_w = 16 * s + l;
#pragma unroll
        for (int u = 0; u < 4; ++u) {
            union { float f; unsigned u; } a0, a1, a2, a3;
            a0.f = acc[u][s][0]; a1.f = acc[u][s][1]; a2.f = acc[u][s][2]; a3.f = acc[u][s][3];
            uint2 pk;
            pk.x = packbf(a0.u, a1.u);
            pk.y = packbf(a2.u, a3.u);
            *(uint2*)&ysl[wv][nl_w][16 * u + 4 * q] = pk;
        }
        if (q == 0) dsl[wv][nl_w] = dacc[s][0];
    }
    __syncthreads();

    // block combine: bf16 partial [p=mh*128+tile][n(64)][64], f32 den [p][64]
    unsigned short* gn = gnum + (size_t)(mh * 128 + tile) * 64 * 64;
    float* gd = gden + (size_t)(mh * 128 + tile) * 64;
    const int nl = t >> 4, og = t & 15;
#pragma unroll
    for (int h = 0; h < 2; ++h) {
        const int nr = nl + 32 * h;
        f32x4 ysum = {0.f, 0.f, 0.f, 0.f};
        float dsum = 0.f;
#pragma unroll
        for (int s = 0; s < 8; ++s) {
            ushort4 p = *(const ushort4*)&ysl[s][nr][og * 4];
            union { unsigned u; float f; } c0, c1, c2, c3;
            c0.u = (unsigned)p.x << 16; c1.u = (unsigned)p.y << 16;
            c2.u = (unsigned)p.z << 16; c3.u = (unsigned)p.w << 16;
            ysum[0] += c0.f; ysum[1] += c1.f; ysum[2] += c2.f; ysum[3] += c3.f;
            dsum += dsl[s][nr];
        }
        ushort4 pk;
        pk.x = f2b(ysum[0]); pk.y = f2b(ysum[1]); pk.z = f2b(ysum[2]); pk.w = f2b(ysum[3]);
        *(ushort4*)(gn + (size_t)nr * 64 + og * 4) = pk;
        if (og == 0) gd[nr] = dsum;
    }
}

// ---------------------------------------------------------------------------
// K2b: epilogue. 256 blocks x 512 thr, 32 nodes each (tile=bx>>1, half=bx&1).
// Combines the two m-half bf16 partials, normalizes, computes node-adaptive
// W in fp32 from adj x wp/bp staged in LDS, writes out.
// ---------------------------------------------------------------------------
__global__ void k_epi2(const float* __restrict__ adj, const float* __restrict__ wp,
                       const float* __restrict__ bp, const float* __restrict__ x,
                       const unsigned short* __restrict__ gnum, const float* __restrict__ gden,
                       float* __restrict__ out) {
    const int t = threadIdx.x;
    const int nl = t >> 4, og = t & 15;           // nl in [0,32)
    const int tile = blockIdx.x >> 1;
    const int half = blockIdx.x & 1;
    const int n0 = blockIdx.x * 32;               // global n base (= tile*64 + half*32)
    const int nloc = half * 32 + nl;              // row within tile partial [0,64)
    const int n = n0 + nl;

    __shared__ float wpl[EMB][5][64];   // 20 KB: [d][c][j], c=4 is bias
    __shared__ float adjl[32][EMB];     // 2 KB
    __shared__ float xl[32][68];
    __shared__ float ylf[32][68];

    // stage wp/bp into LDS (fp32)
    for (int i = t; i < EMB * 5 * 64; i += 512) {
        const int d = i / 320, r = i % 320, c = r >> 6, j = r & 63;
        wpl[d][c][j] = (c < 4) ? wp[(size_t)(d * 4 + c) * 64 + j] : bp[(size_t)d * 64 + j];
    }
    // stage adj rows (one float per thread: 32 x 16 = 512)
    adjl[nl][og] = adj[(size_t)(n0 + nl) * EMB + og];

    // combine the two m-half bf16 partials, normalize
    const unsigned short* gn0 = gnum + (size_t)tile * 64 * 64;
    const unsigned short* gn1 = gnum + (size_t)(128 + tile) * 64 * 64;
    ushort4 p0 = *(const ushort4*)(gn0 + (size_t)nloc * 64 + og * 4);
    ushort4 p1 = *(const ushort4*)(gn1 + (size_t)nloc * 64 + og * 4);
    union { unsigned u; float f; } e0, e1, e2, e3, f0, f1, f2, f3;
    e0.u = (unsigned)p0.x << 16; e1.u = (unsigned)p0.y << 16;
    e2.u = (unsigned)p0.z << 16; e3.u = (unsigned)p0.w << 16;
    f0.u = (unsigned)p1.x << 16; f1.u = (unsigned)p1.y << 16;
    f2.u = (unsigned)p1.z << 16; f3.u = (unsigned)p1.w << 16;
    float dsum = gden[(size_t)tile * 64 + nloc] + gden[(size_t)(128 + tile) * 64 + nloc];
    float rden = 1.f / dsum;
    ylf[nl][og * 4 + 0] = (e0.f + f0.f) * rden;
    ylf[nl][og * 4 + 1] = (e1.f + f1.f) * rden;
    ylf[nl][og * 4 + 2] = (e2.f + f2.f) * rden;
    ylf[nl][og * 4 + 3] = (e3.f + f3.f) * rden;

    // stage x rows
    float2 x0 = *(const float2*)(x + ((size_t)(og * 2) * NN + n) * 2);
    float2 x1v = *(const float2*)(x + ((size_t)(og * 2 + 1) * NN + n) * 2);
    xl[nl][og * 4 + 0] = x0.x; xl[nl][og * 4 + 1] = x0.y;
    xl[nl][og * 4 + 2] = x1v.x; xl[nl][og * 4 + 3] = x1v.y;
    __syncthreads();

    // node-adaptive weights in fp32: W[c][j4] = sum_d adj[n][d] * wpl[d][c][j4]
    float4 W[5];
#pragma unroll
    for (int c = 0; c < 5; ++c) { W[c].x = W[c].y = W[c].z = W[c].w = 0.f; }
#pragma unroll
    for (int d = 0; d < EMB; ++d) {
        const float a = adjl[nl][d];
#pragma unroll
        for (int c = 0; c < 5; ++c) {
            const float4 p = *(const float4*)&wpl[d][c][og * 4];
            W[c].x += a * p.x; W[c].y += a * p.y; W[c].z += a * p.z; W[c].w += a * p.w;
        }
    }

#pragma unroll 4
    for (int b = 0; b < BB; ++b) {
        float xb0 = xl[nl][2 * b], xb1 = xl[nl][2 * b + 1];
        float yb0 = ylf[nl][2 * b], yb1 = ylf[nl][2 * b + 1];
        f32x4 o4;
        o4[0] = xb0 * W[0].x + xb1 * W[1].x + yb0 * W[2].x + yb1 * W[3].x + W[4].x;
        o4[1] = xb0 * W[0].y + xb1 * W[1].y + yb0 * W[2].y + yb1 * W[3].y + W[4].y;
        o4[2] = xb0 * W[0].z + xb1 * W[1].z + yb0 * W[2].z + yb1 * W[3].z + W[4].z;
        o4[3] = xb0 * W[0].w + xb1 * W[1].w + yb0 * W[2].w + yb1 * W[3].w + W[4].w;
        __builtin_nontemporal_store(o4, (f32x4*)(out + ((size_t)b * NN + n) * HID + og * 4));
    }
}

// ---------------------------------------------------------------------------
extern "C" void kernel_launch(void* const* d_in, const int* in_sizes, int n_in,
                              void* d_out, int out_size, void* d_ws, size_t ws_size,
                              hipStream_t stream) {
    const float* x   = (const float*)d_in[0];   // [32, 8192, 2]
    const float* adj = (const float*)d_in[1];   // [8192, 16]
    const float* wp  = (const float*)d_in[2];   // [16, 2, 2, 64]
    const float* bp  = (const float*)d_in[3];   // [16, 64]
    float* out = (float*)d_out;                 // [32, 8192, 64]

    char* w = (char*)d_ws;
    short* VTf   = (short*)w;                                   // 1 MB
    short* Afrag = VTf + (size_t)256 * 4 * 64 * 8;              // 512 KB
    short* adjS  = Afrag + (size_t)256 * 2 * 64 * 8;            // 256 KB
    unsigned short* gnum = (unsigned short*)(adjS + (size_t)NN * EMB);  // 2 MB [256][64][64] bf16
    float* gden  = (float*)(gnum + (size_t)256 * 64 * 64);      // 64 KB [256][64]

    k_build<<<512, 256, 0, stream>>>(x, adj, VTf, Afrag, adjS);
    k_main<<<256, 512, 0, stream>>>(Afrag, adjS, VTf, gnum, gden);
    k_epi2<<<256, 512, 0, stream>>>(adj, wp, bp, x, gnum, gden, out);
}